// Round 8
// baseline (388.934 us; speedup 1.0000x reference)
//
#include <hip/hip_runtime.h>
#include <stdint.h>

typedef unsigned short u16;
typedef unsigned int u32;
typedef __attribute__((ext_vector_type(8))) short bf16x8;
typedef __attribute__((ext_vector_type(4))) float f32x4;

__device__ __forceinline__ u16 f2bf(float f) {
    u32 u = __float_as_uint(f);
    u32 r = (u + 0x7fffu + ((u >> 16) & 1u)) >> 16;
    return (u16)r;
}

// packed RNE f32x2 -> bf16x2: bits[15:0]=bf16(lo), bits[31:16]=bf16(hi)
__device__ __forceinline__ u32 cvtpk(float lo, float hi) {
    u32 r;
    asm("v_cvt_pk_bf16_f32 %0, %1, %2" : "=v"(r) : "v"(lo), "v"(hi));
    return r;
}

__device__ __forceinline__ void gload16(const u16* src, u16* dst) {
    __builtin_amdgcn_global_load_lds(
        (const __attribute__((address_space(1))) u32*)src,
        (__attribute__((address_space(3))) u32*)dst, 16, 0, 0);
}

// ---------------- Kernel 1: BN statistics
__global__ __launch_bounds__(256) void k_stats(const float* __restrict__ x, int n,
                                               float* __restrict__ stats) {
    int t = blockIdx.x * 256 + threadIdx.x;
    int stride = gridDim.x * 256;
    float c = 0.f, s = 0.f, ss = 0.f;
    for (int i = t; i < n; i += stride) {
        float v = x[i];
        if (v != 0.f) { c += 1.f; s += v; ss = fmaf(v, v, ss); }
    }
    for (int off = 32; off > 0; off >>= 1) {
        c  += __shfl_down(c, off);
        s  += __shfl_down(s, off);
        ss += __shfl_down(ss, off);
    }
    __shared__ float red[3][4];
    int lane = threadIdx.x & 63, wv = threadIdx.x >> 6;
    if (lane == 0) { red[0][wv] = c; red[1][wv] = s; red[2][wv] = ss; }
    __syncthreads();
    if (threadIdx.x == 0) {
        atomicAdd(&stats[0], red[0][0] + red[0][1] + red[0][2] + red[0][3]);
        atomicAdd(&stats[1], red[1][0] + red[1][1] + red[1][2] + red[1][3]);
        atomicAdd(&stats[2], red[2][0] + red[2][1] + red[2][2] + red[2][3]);
    }
}

// ---------------- Kernel 2: finalize BN affine
__global__ void k_finalize(const float* __restrict__ g, const float* __restrict__ b,
                           float* __restrict__ stats) {
    float n = stats[0]; if (n < 1.f) n = 1.f;
    float mean = stats[1] / n;
    float var = stats[2] / n - mean * mean;
    if (var < 0.f) var = 0.f;
    float scale = g[0] * rsqrtf(var + 1e-5f);
    stats[4] = scale;
    stats[5] = b[0] - mean * scale;
}

// ---------------- Kernel 2b: merged weight prep
__global__ __launch_bounds__(256) void k_prepall(const float* __restrict__ w2,
    const float* __restrict__ fcw1, u16* __restrict__ w2b, u16* __restrict__ fcw1b, int n)
{
    int i = blockIdx.x * 256 + threadIdx.x;
    if (i < 9 * 64 * 32) {
        int tap = i >> 11, rem = i & 2047, co = rem >> 5, ci = rem & 31;
        w2b[i] = f2bf(w2[tap * 2048 + ci * 64 + co]);
    }
    if (i < n) fcw1b[i] = f2bf(fcw1[i]);
}

// ---------------- Split A: BN-apply + conv1 (VALU) -> h1g global + pool masks
// h1g: per image [g=4][904 slots][8ch] bf16 (57856 B). Halo zeroed here.
__global__ __launch_bounds__(256, 4) void k_conv1(const float* __restrict__ x,
    const float* __restrict__ w1, const float* __restrict__ b1,
    const float* __restrict__ stats, u16* __restrict__ h1g,
    unsigned char* __restrict__ pmg)
{
    __shared__ float feat[30][30];
    __shared__ unsigned char mk[784];
    const int t = threadIdx.x;
    const int b = blockIdx.x;
    const float scale = stats[4], shift = stats[5];

    for (int i = t; i < 900; i += 256) (&feat[0][0])[i] = 0.f;
    __syncthreads();
    const float* xb = x + (size_t)b * 784;
    for (int i = t; i < 784; i += 256) {
        float v = xb[i];
        bool m = (v != 0.f);
        mk[i] = m ? 1 : 0;
        int h = i / 28, w = i - h * 28;
        feat[h + 1][w + 1] = m ? fmaf(v, scale, shift) : 0.f;
    }
    __syncthreads();

    u16* hb_img = h1g + (size_t)b * 28928;

    if (t < 196) {
        int rr = t / 14, cc = t - rr * 14;
        int base = rr * 56 + cc * 2;
        pmg[(size_t)b * 200 + t] = (unsigned char)(mk[base] | (mk[base + 1] << 1)
              | (mk[base + 28] << 2) | (mk[base + 29] << 3));
    }
    if (t < 120) {                       // zero halo + 4 tail slots
        int slot;
        if (t < 30)       slot = t;
        else if (t < 60)  slot = 840 + t;
        else if (t < 88)  slot = (t - 59) * 30;
        else if (t < 116) slot = (t - 87) * 30 + 29;
        else              slot = 784 + t;
        const uint4 z = make_uint4(0u, 0u, 0u, 0u);
        #pragma unroll
        for (int g = 0; g < 4; ++g)
            *(uint4*)&hb_img[g * 7232 + slot * 8] = z;
    }

    const int cp = (t >> 4) & 3;
    const int pxg = (t & 15) | ((t >> 6) << 4);
    float wk[9][8], bs[8];
    {
        float4 b0 = *(const float4*)(b1 + cp * 8);
        float4 b4 = *(const float4*)(b1 + cp * 8 + 4);
        bs[0]=b0.x; bs[1]=b0.y; bs[2]=b0.z; bs[3]=b0.w;
        bs[4]=b4.x; bs[5]=b4.y; bs[6]=b4.z; bs[7]=b4.w;
    }
    #pragma unroll
    for (int j = 0; j < 9; ++j) {
        float4 w0 = *(const float4*)(w1 + j * 32 + cp * 8);
        float4 w4 = *(const float4*)(w1 + j * 32 + cp * 8 + 4);
        wk[j][0]=w0.x; wk[j][1]=w0.y; wk[j][2]=w0.z; wk[j][3]=w0.w;
        wk[j][4]=w4.x; wk[j][5]=w4.y; wk[j][6]=w4.z; wk[j][7]=w4.w;
    }
    u16* hb = hb_img + cp * 7232;
    for (int px = pxg; px < 784; px += 64) {
        int h = px / 28, w = px - h * 28;
        float a[8];
        #pragma unroll
        for (int c = 0; c < 8; ++c) a[c] = bs[c];
        #pragma unroll
        for (int kh = 0; kh < 3; ++kh)
            #pragma unroll
            for (int kw = 0; kw < 3; ++kw) {
                float f = feat[h + kh][w + kw];
                #pragma unroll
                for (int c = 0; c < 8; ++c) a[c] = fmaf(f, wk[kh * 3 + kw][c], a[c]);
            }
        float mf = mk[px] ? 1.f : 0.f;
        u32 q0 = cvtpk(fmaxf(a[0], 0.f) * mf, fmaxf(a[1], 0.f) * mf);
        u32 q1 = cvtpk(fmaxf(a[2], 0.f) * mf, fmaxf(a[3], 0.f) * mf);
        u32 q2 = cvtpk(fmaxf(a[4], 0.f) * mf, fmaxf(a[5], 0.f) * mf);
        u32 q3 = cvtpk(fmaxf(a[6], 0.f) * mf, fmaxf(a[7], 0.f) * mf);
        *(uint4*)&hb[((h + 1) * 30 + (w + 1)) * 8] = make_uint4(q0, q1, q2, q3);
    }
}

// ---------------- Split B: conv2 (MFMA) + mask + ReLU + pool (linear gload_lds staging)
__global__ __launch_bounds__(256, 2) void k_conv2(const u16* __restrict__ h1g,
    const unsigned char* __restrict__ pmg, const u16* __restrict__ w2b,
    const float* __restrict__ b2, u16* __restrict__ pooled)
{
    __shared__ u16 h1[28928];
    __shared__ unsigned char pm[200];
    const int t = threadIdx.x;
    const int b = blockIdx.x;
    const int lane = t & 63;
    const int wv = t >> 6;
    const int lg = lane >> 4;
    const int lr = lane & 15;

    const u16* src = h1g + (size_t)b * 28928;
    #pragma unroll
    for (int i = 0; i < 14; ++i)
        gload16(src + (i * 256 + t) * 8, &h1[(i * 256 + t) * 8]);
    if (t < 32) {
        uint4 v = *(const uint4*)(src + (3584 + t) * 8);
        *(uint4*)&h1[(3584 + t) * 8] = v;
    }
    if (t < 50) ((u32*)pm)[t] = ((const u32*)(pmg + (size_t)b * 200))[t];

    bf16x8 wf[9][4];
    #pragma unroll
    for (int tap = 0; tap < 9; ++tap)
        #pragma unroll
        for (int nt = 0; nt < 4; ++nt)
            wf[tap][nt] = *(const bf16x8*)(w2b + tap * 2048 + (nt * 16 + lr) * 32 + lg * 8);
    float bias2[4];
    #pragma unroll
    for (int nt = 0; nt < 4; ++nt) bias2[nt] = b2[nt * 16 + lr];

    asm volatile("s_waitcnt vmcnt(0)" ::: "memory");
    __syncthreads();

    const int cb = wv & 1;
    const int r0 = wv >> 1;
    const char* gb = (const char*)h1 + lg * 14464 + (cb * 16 + lr) * 16;
    const bool store_ok = !(cb == 1 && lg == 3);
    const int pc0 = cb * 8 + lg * 2;
    u16* poolb = pooled + (size_t)b * 12544;

    #pragma unroll 1
    for (int i = 0; i < 7; ++i) {
        const int r = r0 + 2 * i;
        const char* ab = gb + 960 * r;
        bf16x8 a0[3], a1[3], a2[3], a3[3];
        #pragma unroll
        for (int kw = 0; kw < 3; ++kw) {
            a0[kw] = *(const bf16x8*)(ab + kw * 16);
            a1[kw] = *(const bf16x8*)(ab + 480 + kw * 16);
            a2[kw] = *(const bf16x8*)(ab + 960 + kw * 16);
        }
        f32x4 acc0[4], acc1[4];
        #pragma unroll
        for (int nt = 0; nt < 4; ++nt) {
            acc0[nt] = (f32x4){bias2[nt], bias2[nt], bias2[nt], bias2[nt]};
            acc1[nt] = acc0[nt];
        }
        #pragma unroll
        for (int nt = 0; nt < 4; ++nt)
            #pragma unroll
            for (int kw = 0; kw < 3; ++kw) {
                acc0[nt] = __builtin_amdgcn_mfma_f32_16x16x32_bf16(a0[kw], wf[kw][nt], acc0[nt], 0, 0, 0);
                acc0[nt] = __builtin_amdgcn_mfma_f32_16x16x32_bf16(a1[kw], wf[3 + kw][nt], acc0[nt], 0, 0, 0);
                acc0[nt] = __builtin_amdgcn_mfma_f32_16x16x32_bf16(a2[kw], wf[6 + kw][nt], acc0[nt], 0, 0, 0);
            }
        #pragma unroll
        for (int kw = 0; kw < 3; ++kw)
            a3[kw] = *(const bf16x8*)(ab + 1440 + kw * 16);
        #pragma unroll
        for (int nt = 0; nt < 4; ++nt)
            #pragma unroll
            for (int kw = 0; kw < 3; ++kw) {
                acc1[nt] = __builtin_amdgcn_mfma_f32_16x16x32_bf16(a1[kw], wf[kw][nt], acc1[nt], 0, 0, 0);
                acc1[nt] = __builtin_amdgcn_mfma_f32_16x16x32_bf16(a2[kw], wf[3 + kw][nt], acc1[nt], 0, 0, 0);
                acc1[nt] = __builtin_amdgcn_mfma_f32_16x16x32_bf16(a3[kw], wf[6 + kw][nt], acc1[nt], 0, 0, 0);
            }

        if (store_ok) {
            u32 pmw = *(const u16*)&pm[r * 14 + pc0];
            float m00 = (pmw & 1u)    ? 1.f : 0.f, m01 = (pmw & 2u)    ? 1.f : 0.f;
            float m10 = (pmw & 4u)    ? 1.f : 0.f, m11 = (pmw & 8u)    ? 1.f : 0.f;
            float n00 = (pmw & 256u)  ? 1.f : 0.f, n01 = (pmw & 512u)  ? 1.f : 0.f;
            float n10 = (pmw & 1024u) ? 1.f : 0.f, n11 = (pmw & 2048u) ? 1.f : 0.f;
            #pragma unroll
            for (int nt = 0; nt < 4; ++nt) {
                float p0 = fmaxf(fmaxf(fmaxf(acc0[nt][0], 0.f) * m00, fmaxf(acc0[nt][1], 0.f) * m01),
                                 fmaxf(fmaxf(acc1[nt][0], 0.f) * m10, fmaxf(acc1[nt][1], 0.f) * m11));
                float p1 = fmaxf(fmaxf(fmaxf(acc0[nt][2], 0.f) * n00, fmaxf(acc0[nt][3], 0.f) * n01),
                                 fmaxf(fmaxf(acc1[nt][2], 0.f) * n10, fmaxf(acc1[nt][3], 0.f) * n11));
                *(u32*)&poolb[(nt * 16 + lr) * 196 + r * 14 + pc0] = cvtpk(p0, p1);
            }
        }
    }
}

// ---------------- Fallback monolith (R6 structure + branchless conv1 + cvt_pk)
__global__ __launch_bounds__(256, 2) void k_conv(const float* __restrict__ x,
    const float* __restrict__ w1, const float* __restrict__ b1,
    const u16* __restrict__ w2b, const float* __restrict__ b2,
    const float* __restrict__ stats, u16* __restrict__ pooled)
{
    __shared__ u16 h1[28928];
    __shared__ float feat[30][30];
    __shared__ unsigned char mk[784];
    __shared__ unsigned char pm[200];
    const int t = threadIdx.x;
    const int b = blockIdx.x;
    const int lane = t & 63;
    const int wv = t >> 6;
    const int lg = lane >> 4;
    const int lr = lane & 15;

    const float scale = stats[4], shift = stats[5];

    for (int i = t; i < 900; i += 256) (&feat[0][0])[i] = 0.f;
    if (t < 120) {                       // zero only halo + tail of h1
        int slot;
        if (t < 30)       slot = t;
        else if (t < 60)  slot = 840 + t;
        else if (t < 88)  slot = (t - 59) * 30;
        else if (t < 116) slot = (t - 87) * 30 + 29;
        else              slot = 784 + t;
        const uint4 z = make_uint4(0u, 0u, 0u, 0u);
        #pragma unroll
        for (int g = 0; g < 4; ++g)
            *(uint4*)&h1[g * 7232 + slot * 8] = z;
    }
    __syncthreads();

    const float* xb = x + (size_t)b * 784;
    for (int i = t; i < 784; i += 256) {
        float v = xb[i];
        bool m = (v != 0.f);
        mk[i] = m ? 1 : 0;
        int h = i / 28, w = i - h * 28;
        feat[h + 1][w + 1] = m ? fmaf(v, scale, shift) : 0.f;
    }
    __syncthreads();

    if (t < 196) {
        int rr = t / 14, cc = t - rr * 14;
        int base = rr * 56 + cc * 2;
        pm[t] = (unsigned char)(mk[base] | (mk[base + 1] << 1)
              | (mk[base + 28] << 2) | (mk[base + 29] << 3));
    }

    {
        const int cp = (t >> 4) & 3;
        const int pxg = (t & 15) | ((t >> 6) << 4);
        float wk[9][8], bs[8];
        {
            float4 b0 = *(const float4*)(b1 + cp * 8);
            float4 b4 = *(const float4*)(b1 + cp * 8 + 4);
            bs[0]=b0.x; bs[1]=b0.y; bs[2]=b0.z; bs[3]=b0.w;
            bs[4]=b4.x; bs[5]=b4.y; bs[6]=b4.z; bs[7]=b4.w;
        }
        #pragma unroll
        for (int j = 0; j < 9; ++j) {
            float4 w0 = *(const float4*)(w1 + j * 32 + cp * 8);
            float4 w4 = *(const float4*)(w1 + j * 32 + cp * 8 + 4);
            wk[j][0]=w0.x; wk[j][1]=w0.y; wk[j][2]=w0.z; wk[j][3]=w0.w;
            wk[j][4]=w4.x; wk[j][5]=w4.y; wk[j][6]=w4.z; wk[j][7]=w4.w;
        }
        char* hb = (char*)h1 + cp * 14464;
        for (int px = pxg; px < 784; px += 64) {
            int h = px / 28, w = px - h * 28;
            float a[8];
            #pragma unroll
            for (int c = 0; c < 8; ++c) a[c] = bs[c];
            #pragma unroll
            for (int kh = 0; kh < 3; ++kh)
                #pragma unroll
                for (int kw = 0; kw < 3; ++kw) {
                    float f = feat[h + kh][w + kw];
                    #pragma unroll
                    for (int c = 0; c < 8; ++c) a[c] = fmaf(f, wk[kh * 3 + kw][c], a[c]);
                }
            float mf = mk[px] ? 1.f : 0.f;
            u32 q0 = cvtpk(fmaxf(a[0], 0.f) * mf, fmaxf(a[1], 0.f) * mf);
            u32 q1 = cvtpk(fmaxf(a[2], 0.f) * mf, fmaxf(a[3], 0.f) * mf);
            u32 q2 = cvtpk(fmaxf(a[4], 0.f) * mf, fmaxf(a[5], 0.f) * mf);
            u32 q3 = cvtpk(fmaxf(a[6], 0.f) * mf, fmaxf(a[7], 0.f) * mf);
            *(uint4*)(hb + ((h + 1) * 30 + (w + 1)) * 16) = make_uint4(q0, q1, q2, q3);
        }
    }
    __syncthreads();

    bf16x8 wf[9][4];
    #pragma unroll
    for (int tap = 0; tap < 9; ++tap)
        #pragma unroll
        for (int nt = 0; nt < 4; ++nt)
            wf[tap][nt] = *(const bf16x8*)(w2b + tap * 2048 + (nt * 16 + lr) * 32 + lg * 8);
    float bias2[4];
    #pragma unroll
    for (int nt = 0; nt < 4; ++nt) bias2[nt] = b2[nt * 16 + lr];

    const int cb = wv & 1;
    const int r0 = wv >> 1;
    const char* gb = (const char*)h1 + lg * 14464 + (cb * 16 + lr) * 16;
    const bool store_ok = !(cb == 1 && lg == 3);
    const int pc0 = cb * 8 + lg * 2;
    u16* poolb = pooled + (size_t)b * 12544;

    #pragma unroll 1
    for (int i = 0; i < 7; ++i) {
        const int r = r0 + 2 * i;
        const char* ab = gb + 960 * r;
        bf16x8 a0[3], a1[3], a2[3], a3[3];
        #pragma unroll
        for (int kw = 0; kw < 3; ++kw) {
            a0[kw] = *(const bf16x8*)(ab + kw * 16);
            a1[kw] = *(const bf16x8*)(ab + 480 + kw * 16);
            a2[kw] = *(const bf16x8*)(ab + 960 + kw * 16);
        }
        f32x4 acc0[4], acc1[4];
        #pragma unroll
        for (int nt = 0; nt < 4; ++nt) {
            acc0[nt] = (f32x4){bias2[nt], bias2[nt], bias2[nt], bias2[nt]};
            acc1[nt] = acc0[nt];
        }
        #pragma unroll
        for (int nt = 0; nt < 4; ++nt)
            #pragma unroll
            for (int kw = 0; kw < 3; ++kw) {
                acc0[nt] = __builtin_amdgcn_mfma_f32_16x16x32_bf16(a0[kw], wf[kw][nt], acc0[nt], 0, 0, 0);
                acc0[nt] = __builtin_amdgcn_mfma_f32_16x16x32_bf16(a1[kw], wf[3 + kw][nt], acc0[nt], 0, 0, 0);
                acc0[nt] = __builtin_amdgcn_mfma_f32_16x16x32_bf16(a2[kw], wf[6 + kw][nt], acc0[nt], 0, 0, 0);
            }
        #pragma unroll
        for (int kw = 0; kw < 3; ++kw)
            a3[kw] = *(const bf16x8*)(ab + 1440 + kw * 16);
        #pragma unroll
        for (int nt = 0; nt < 4; ++nt)
            #pragma unroll
            for (int kw = 0; kw < 3; ++kw) {
                acc1[nt] = __builtin_amdgcn_mfma_f32_16x16x32_bf16(a1[kw], wf[kw][nt], acc1[nt], 0, 0, 0);
                acc1[nt] = __builtin_amdgcn_mfma_f32_16x16x32_bf16(a2[kw], wf[3 + kw][nt], acc1[nt], 0, 0, 0);
                acc1[nt] = __builtin_amdgcn_mfma_f32_16x16x32_bf16(a3[kw], wf[6 + kw][nt], acc1[nt], 0, 0, 0);
            }

        if (store_ok) {
            u32 pmw = *(const u16*)&pm[r * 14 + pc0];
            float m00 = (pmw & 1u)    ? 1.f : 0.f, m01 = (pmw & 2u)    ? 1.f : 0.f;
            float m10 = (pmw & 4u)    ? 1.f : 0.f, m11 = (pmw & 8u)    ? 1.f : 0.f;
            float n00 = (pmw & 256u)  ? 1.f : 0.f, n01 = (pmw & 512u)  ? 1.f : 0.f;
            float n10 = (pmw & 1024u) ? 1.f : 0.f, n11 = (pmw & 2048u) ? 1.f : 0.f;
            #pragma unroll
            for (int nt = 0; nt < 4; ++nt) {
                float p0 = fmaxf(fmaxf(fmaxf(acc0[nt][0], 0.f) * m00, fmaxf(acc0[nt][1], 0.f) * m01),
                                 fmaxf(fmaxf(acc1[nt][0], 0.f) * m10, fmaxf(acc1[nt][1], 0.f) * m11));
                float p1 = fmaxf(fmaxf(fmaxf(acc0[nt][2], 0.f) * n00, fmaxf(acc0[nt][3], 0.f) * n01),
                                 fmaxf(fmaxf(acc1[nt][2], 0.f) * n10, fmaxf(acc1[nt][3], 0.f) * n11));
                *(u32*)&poolb[(nt * 16 + lr) * 196 + r * 14 + pc0] = cvtpk(p0, p1);
            }
        }
    }
}

// ---------------- Kernel 4: FC1 MFMA GEMM (BM=64,BN=128,BK=64,splitK=7)
__global__ __launch_bounds__(256, 4) void k_fc1(const u16* __restrict__ pooled,
    const u16* __restrict__ fcw1b, float* __restrict__ fc1, int M)
{
    __shared__ u16 Asm[8 * 64 * 8];
    __shared__ u16 Bsm[8 * 128 * 8];
    const int t = threadIdx.x;
    const int m0 = blockIdx.x * 64;
    const int kbase = blockIdx.y * 1792;
    const int lane = t & 63;
    const int wv = t >> 6;
    const int lg = lane >> 4, lr = lane & 15;
    const int wm = wv & 1, wn = wv >> 1;

    const int ia0 = t, ia1 = t + 256;
    const u16* as0 = pooled + (size_t)(m0 + (ia0 & 63)) * 12544 + (ia0 >> 6) * 8 + kbase;
    const u16* as1 = pooled + (size_t)(m0 + (ia1 & 63)) * 12544 + (ia1 >> 6) * 8 + kbase;
    const u16* bs0 = fcw1b + (size_t)(t & 127) * 12544 + ((t >> 7) + 0) * 8 + kbase;
    const u16* bs1 = fcw1b + (size_t)(t & 127) * 12544 + ((t >> 7) + 2) * 8 + kbase;
    const u16* bs2 = fcw1b + (size_t)(t & 127) * 12544 + ((t >> 7) + 4) * 8 + kbase;
    const u16* bs3 = fcw1b + (size_t)(t & 127) * 12544 + ((t >> 7) + 6) * 8 + kbase;
    u16* ad0 = &Asm[(size_t)ia0 * 8];
    u16* ad1 = &Asm[(size_t)ia1 * 8];
    u16* bd0 = &Bsm[(size_t)(t + 0) * 8];
    u16* bd1 = &Bsm[(size_t)(t + 256) * 8];
    u16* bd2 = &Bsm[(size_t)(t + 512) * 8];
    u16* bd3 = &Bsm[(size_t)(t + 768) * 8];

    f32x4 acc[2][4];
    #pragma unroll
    for (int mi = 0; mi < 2; ++mi)
        #pragma unroll
        for (int ni = 0; ni < 4; ++ni) acc[mi][ni] = (f32x4){0.f, 0.f, 0.f, 0.f};

    for (int s = 0; s < 28; ++s) {
        const int kk = s * 64;
        __syncthreads();
        gload16(as0 + kk, ad0);
        gload16(as1 + kk, ad1);
        gload16(bs0 + kk, bd0);
        gload16(bs1 + kk, bd1);
        gload16(bs2 + kk, bd2);
        gload16(bs3 + kk, bd3);
        asm volatile("s_waitcnt vmcnt(0)" ::: "memory");
        __syncthreads();
        #pragma unroll
        for (int ks = 0; ks < 2; ++ks) {
            bf16x8 a[2], bfr[4];
            #pragma unroll
            for (int mi = 0; mi < 2; ++mi)
                a[mi] = *(const bf16x8*)&Asm[(((ks * 4 + lg) * 64) + wm * 32 + mi * 16 + lr) * 8];
            #pragma unroll
            for (int ni = 0; ni < 4; ++ni)
                bfr[ni] = *(const bf16x8*)&Bsm[(((ks * 4 + lg) * 128) + wn * 64 + ni * 16 + lr) * 8];
            #pragma unroll
            for (int mi = 0; mi < 2; ++mi)
                #pragma unroll
                for (int ni = 0; ni < 4; ++ni)
                    acc[mi][ni] = __builtin_amdgcn_mfma_f32_16x16x32_bf16(a[mi], bfr[ni], acc[mi][ni], 0, 0, 0);
        }
    }

    #pragma unroll
    for (int mi = 0; mi < 2; ++mi)
        #pragma unroll
        for (int ni = 0; ni < 4; ++ni)
            #pragma unroll
            for (int q = 0; q < 4; ++q) {
                int m = m0 + wm * 32 + mi * 16 + lg * 4 + q;
                int n = wn * 64 + ni * 16 + lr;
                atomicAdd(&fc1[(size_t)m * 128 + n], acc[mi][ni][q]);
            }
}

// ---------------- Kernel 5: bias+ReLU + FC2 + log_softmax
__global__ __launch_bounds__(256) void k_fc2(const float* __restrict__ fc1,
    const float* __restrict__ fcb1, const float* __restrict__ fcw2,
    const float* __restrict__ fcb2, float* __restrict__ out, int M)
{
    __shared__ float red[8][32][10];
    const int t = threadIdx.x;
    const int ml = t & 31, kq = t >> 5;
    const int m = blockIdx.x * 32 + ml;
    float acc[10];
    #pragma unroll
    for (int c = 0; c < 10; ++c) acc[c] = 0.f;
    const float* fp = fc1 + (size_t)m * 128 + kq * 16;
    #pragma unroll
    for (int j = 0; j < 16; j += 4) {
        float4 v4 = *(const float4*)(fp + j);
        float vv[4] = {v4.x, v4.y, v4.z, v4.w};
        #pragma unroll
        for (int u = 0; u < 4; ++u) {
            int k = kq * 16 + j + u;
            float v = fmaxf(vv[u] + fcb1[k], 0.f);
            #pragma unroll
            for (int c = 0; c < 10; ++c) acc[c] = fmaf(v, fcw2[c * 128 + k], acc[c]);
        }
    }
    #pragma unroll
    for (int c = 0; c < 10; ++c) red[kq][ml][c] = acc[c];
    __syncthreads();
    if (kq == 0) {
        float lgt[10];
        #pragma unroll
        for (int c = 0; c < 10; ++c) {
            float sv = 0.f;
            #pragma unroll
            for (int s = 0; s < 8; ++s) sv += red[s][ml][c];
            lgt[c] = sv + fcb2[c];
        }
        float mx = lgt[0];
        #pragma unroll
        for (int c = 1; c < 10; ++c) mx = fmaxf(mx, lgt[c]);
        float se = 0.f;
        #pragma unroll
        for (int c = 0; c < 10; ++c) se += expf(lgt[c] - mx);
        float lse = mx + logf(se);
        #pragma unroll
        for (int c = 0; c < 10; ++c) out[(size_t)m * 10 + c] = lgt[c] - lse;
    }
}

extern "C" void kernel_launch(void* const* d_in, const int* in_sizes, int n_in,
                              void* d_out, int out_size, void* d_ws, size_t ws_size,
                              hipStream_t stream) {
    const float* x     = (const float*)d_in[0];
    const float* gamma = (const float*)d_in[1];
    const float* beta  = (const float*)d_in[2];
    const float* w1    = (const float*)d_in[3];
    const float* b1    = (const float*)d_in[4];
    const float* w2    = (const float*)d_in[5];
    const float* b2    = (const float*)d_in[6];
    const float* fcw1  = (const float*)d_in[7];
    const float* fcb1  = (const float*)d_in[8];
    const float* fcw2  = (const float*)d_in[9];
    const float* fcb2  = (const float*)d_in[10];
    float* out = (float*)d_out;

    const int B = in_sizes[0] / 784;  // 4096
    char* base = (char*)d_ws;
    float* stats = (float*)base;

    // --- Split layout: stats | w2b(36864) | pmg(B*200) | region1{h1g(CH*57856) / fc1}
    //                   | pooled(B*25088) | fcw1b(128*25088)
    const size_t o_w2b = 256;
    const size_t o_pmg = 37376;                     // 256 + 36864, 256-aligned
    const size_t o_r1  = o_pmg + (size_t)B * 200;   // B=4096 -> 856576
    const size_t tail  = (size_t)B * 25088 + (size_t)128 * 25088;
    long long avail = (long long)ws_size - (long long)(o_r1 + tail);
    int CH = avail > 0 ? (int)(avail / 57856) : 0;
    if (CH > B) CH = B;
    const bool use_split = (CH >= 512);

    hipMemsetAsync(stats, 0, 32, stream);
    k_stats<<<1024, 256, 0, stream>>>(x, B * 784, stats);
    k_finalize<<<1, 1, 0, stream>>>(gamma, beta, stats);

    if (use_split) {
        u16* w2b = (u16*)(base + o_w2b);
        unsigned char* pmg = (unsigned char*)(base + o_pmg);
        u16* h1g = (u16*)(base + o_r1);
        float* fc1 = (float*)(base + o_r1);              // aliased; live after conv
        u16* pooled = (u16*)(base + o_r1 + (size_t)CH * 57856);
        u16* fcw1b = (u16*)((char*)pooled + (size_t)B * 25088);

        k_prepall<<<(128 * 12544 + 255) / 256, 256, 0, stream>>>(w2, fcw1, w2b, fcw1b, 128 * 12544);
        for (int c0 = 0; c0 < B; c0 += CH) {
            int nb = (B - c0 < CH) ? (B - c0) : CH;
            k_conv1<<<nb, 256, 0, stream>>>(x + (size_t)c0 * 784, w1, b1, stats,
                                            h1g, pmg + (size_t)c0 * 200);
            k_conv2<<<nb, 256, 0, stream>>>(h1g, pmg + (size_t)c0 * 200, w2b, b2,
                                            pooled + (size_t)c0 * 12544);
        }
        hipMemsetAsync(fc1, 0, (size_t)B * 128 * 4, stream);
        k_fc1<<<dim3(B / 64, 7), 256, 0, stream>>>(pooled, fcw1b, fc1, B);
        k_fc2<<<B / 32, 256, 0, stream>>>(fc1, fcb1, fcw2, fcb2, out, B);
    } else {
        // R6-proven layout: stats | fc1/w2b @256 | pooled | fcw1b
        u16* w2b = (u16*)(base + 256);
        float* fc1 = (float*)(base + 256);
        u16* pooled = (u16*)(base + 256 + (size_t)B * 512);
        u16* fcw1b = (u16*)(base + 256 + (size_t)B * 512 + (size_t)B * 25088);

        k_prepall<<<(128 * 12544 + 255) / 256, 256, 0, stream>>>(w2, fcw1, w2b, fcw1b, 128 * 12544);
        k_conv<<<B, 256, 0, stream>>>(x, w1, b1, w2b, b2, stats, pooled);
        hipMemsetAsync(fc1, 0, (size_t)B * 128 * 4, stream);
        k_fc1<<<dim3(B / 64, 7), 256, 0, stream>>>(pooled, fcw1b, fc1, B);
        k_fc2<<<B / 32, 256, 0, stream>>>(fc1, fcb1, fcw2, fcb2, out, B);
    }
}

// Round 9
// 322.989 us; speedup vs baseline: 1.2042x; 1.2042x over previous
//
#include <hip/hip_runtime.h>
#include <stdint.h>

typedef unsigned short u16;
typedef unsigned int u32;
typedef __attribute__((ext_vector_type(8))) short bf16x8;
typedef __attribute__((ext_vector_type(4))) float f32x4;

__device__ __forceinline__ u16 f2bf(float f) {
    u32 u = __float_as_uint(f);
    u32 r = (u + 0x7fffu + ((u >> 16) & 1u)) >> 16;
    return (u16)r;
}

// packed RNE f32x2 -> bf16x2: bits[15:0]=bf16(lo), bits[31:16]=bf16(hi)
__device__ __forceinline__ u32 cvtpk(float lo, float hi) {
    u32 r;
    asm("v_cvt_pk_bf16_f32 %0, %1, %2" : "=v"(r) : "v"(lo), "v"(hi));
    return r;
}

__device__ __forceinline__ void gload16(const u16* src, u16* dst) {
    __builtin_amdgcn_global_load_lds(
        (const __attribute__((address_space(1))) u32*)src,
        (__attribute__((address_space(3))) u32*)dst, 16, 0, 0);
}

// ---------------- Kernel 1: BN statistics
__global__ __launch_bounds__(256) void k_stats(const float* __restrict__ x, int n,
                                               float* __restrict__ stats) {
    int t = blockIdx.x * 256 + threadIdx.x;
    int stride = gridDim.x * 256;
    float c = 0.f, s = 0.f, ss = 0.f;
    for (int i = t; i < n; i += stride) {
        float v = x[i];
        if (v != 0.f) { c += 1.f; s += v; ss = fmaf(v, v, ss); }
    }
    for (int off = 32; off > 0; off >>= 1) {
        c  += __shfl_down(c, off);
        s  += __shfl_down(s, off);
        ss += __shfl_down(ss, off);
    }
    __shared__ float red[3][4];
    int lane = threadIdx.x & 63, wv = threadIdx.x >> 6;
    if (lane == 0) { red[0][wv] = c; red[1][wv] = s; red[2][wv] = ss; }
    __syncthreads();
    if (threadIdx.x == 0) {
        atomicAdd(&stats[0], red[0][0] + red[0][1] + red[0][2] + red[0][3]);
        atomicAdd(&stats[1], red[1][0] + red[1][1] + red[1][2] + red[1][3]);
        atomicAdd(&stats[2], red[2][0] + red[2][1] + red[2][2] + red[2][3]);
    }
}

// ---------------- Kernel 2: finalize BN affine
__global__ void k_finalize(const float* __restrict__ g, const float* __restrict__ b,
                           float* __restrict__ stats) {
    float n = stats[0]; if (n < 1.f) n = 1.f;
    float mean = stats[1] / n;
    float var = stats[2] / n - mean * mean;
    if (var < 0.f) var = 0.f;
    float scale = g[0] * rsqrtf(var + 1e-5f);
    stats[4] = scale;
    stats[5] = b[0] - mean * scale;
}

// ---------------- Kernel 2b: weight prep (w2 -> w2b bf16 transposed; fcw1 -> bf16 x4)
__global__ __launch_bounds__(256) void k_prepall(const float* __restrict__ w2,
    const float* __restrict__ fcw1, u16* __restrict__ w2b, u16* __restrict__ fcw1b, int n4)
{
    int i = blockIdx.x * 256 + threadIdx.x;
    if (i < 9 * 64 * 32) {
        int tap = i >> 11, rem = i & 2047, co = rem >> 5, ci = rem & 31;
        w2b[i] = f2bf(w2[tap * 2048 + ci * 64 + co]);
    }
    if (i < n4) {
        float4 v = *(const float4*)(fcw1 + (size_t)i * 4);
        *(uint2*)(fcw1b + (size_t)i * 4) = make_uint2(cvtpk(v.x, v.y), cvtpk(v.z, v.w));
    }
}

// ---------------- Kernel 3: fused BN-apply + conv1 (rolling-window VALU) + conv2 (MFMA) + pool
// 256 threads (4 waves), 1 image/block, 2 blocks/CU.
// conv1: thread group pxg (0..55 active) = half-row of 14 consecutive px; 3x3 window
// rolls along w (3 new LDS reads/px), no integer division, linear h1 writes.
// conv2: m-tile = 16 consecutive px of one row (contiguous conflict-free ds_read_b128);
// per wave full n, row-pair jobs, 12 unique A-frags per 72 MFMAs. Pool in-lane.
__global__ __launch_bounds__(256, 2) void k_conv(const float* __restrict__ x,
    const float* __restrict__ w1, const float* __restrict__ b1,
    const u16* __restrict__ w2b, const float* __restrict__ b2,
    const float* __restrict__ stats, u16* __restrict__ pooled)
{
    __shared__ u16 h1[28928];            // [g=4][904 slots][8ch] bf16 (57856 B)
    __shared__ float feat[30][30];
    __shared__ unsigned char mk[784];
    __shared__ unsigned char pm[200];
    const int t = threadIdx.x;
    const int b = blockIdx.x;
    const int lane = t & 63;
    const int wv = t >> 6;
    const int lg = lane >> 4;
    const int lr = lane & 15;

    const float scale = stats[4], shift = stats[5];

    for (int i = t; i < 900; i += 256) (&feat[0][0])[i] = 0.f;
    if (t < 120) {                       // zero only halo + tail of h1
        int slot;
        if (t < 30)       slot = t;
        else if (t < 60)  slot = 840 + t;
        else if (t < 88)  slot = (t - 59) * 30;
        else if (t < 116) slot = (t - 87) * 30 + 29;
        else              slot = 784 + t;
        const uint4 z = make_uint4(0u, 0u, 0u, 0u);
        #pragma unroll
        for (int g = 0; g < 4; ++g)
            *(uint4*)&h1[g * 7232 + slot * 8] = z;
    }
    __syncthreads();

    const float* xb = x + (size_t)b * 784;
    for (int i = t; i < 784; i += 256) {
        float v = xb[i];
        bool m = (v != 0.f);
        mk[i] = m ? 1 : 0;
        int h = i / 28, w = i - h * 28;
        feat[h + 1][w + 1] = m ? fmaf(v, scale, shift) : 0.f;
    }
    __syncthreads();

    if (t < 196) {
        int rr = t / 14, cc = t - rr * 14;
        int base = rr * 56 + cc * 2;
        pm[t] = (unsigned char)(mk[base] | (mk[base + 1] << 1)
              | (mk[base + 28] << 2) | (mk[base + 29] << 3));
    }

    // conv1: half-row rolling window, 8 output channels per thread
    {
        const int cp = (t >> 4) & 3;                 // channel octet = h1 group
        const int pxg = (t & 15) | ((t >> 6) << 4);  // 0..63; >=56 idle
        if (pxg < 56) {
            const int hh = 1 + (pxg >> 1);           // padded row 1..28
            const int wb = (pxg & 1) * 14;           // unpadded col base
            float wk[9][8], bs[8];
            {
                float4 b0 = *(const float4*)(b1 + cp * 8);
                float4 b4 = *(const float4*)(b1 + cp * 8 + 4);
                bs[0]=b0.x; bs[1]=b0.y; bs[2]=b0.z; bs[3]=b0.w;
                bs[4]=b4.x; bs[5]=b4.y; bs[6]=b4.z; bs[7]=b4.w;
            }
            #pragma unroll
            for (int j = 0; j < 9; ++j) {
                float4 w0 = *(const float4*)(w1 + j * 32 + cp * 8);
                float4 w4 = *(const float4*)(w1 + j * 32 + cp * 8 + 4);
                wk[j][0]=w0.x; wk[j][1]=w0.y; wk[j][2]=w0.z; wk[j][3]=w0.w;
                wk[j][4]=w4.x; wk[j][5]=w4.y; wk[j][6]=w4.z; wk[j][7]=w4.w;
            }
            char* hb = (char*)h1 + cp * 14464 + (hh * 30 + wb + 1) * 16;
            const int pxbase = (hh - 1) * 28 + wb;
            float c0[3], c1[3], c2[3];
            #pragma unroll
            for (int r = 0; r < 3; ++r) {
                c0[r] = feat[hh - 1 + r][wb + 0];
                c1[r] = feat[hh - 1 + r][wb + 1];
            }
            #pragma unroll 2
            for (int j = 0; j < 14; ++j) {
                #pragma unroll
                for (int r = 0; r < 3; ++r) c2[r] = feat[hh - 1 + r][wb + j + 2];
                float a[8];
                #pragma unroll
                for (int c = 0; c < 8; ++c) a[c] = bs[c];
                #pragma unroll
                for (int r = 0; r < 3; ++r) {
                    #pragma unroll
                    for (int c = 0; c < 8; ++c) {
                        a[c] = fmaf(c0[r], wk[r * 3 + 0][c], a[c]);
                        a[c] = fmaf(c1[r], wk[r * 3 + 1][c], a[c]);
                        a[c] = fmaf(c2[r], wk[r * 3 + 2][c], a[c]);
                    }
                }
                float mf = mk[pxbase + j] ? 1.f : 0.f;
                u32 q0 = cvtpk(fmaxf(a[0], 0.f) * mf, fmaxf(a[1], 0.f) * mf);
                u32 q1 = cvtpk(fmaxf(a[2], 0.f) * mf, fmaxf(a[3], 0.f) * mf);
                u32 q2 = cvtpk(fmaxf(a[4], 0.f) * mf, fmaxf(a[5], 0.f) * mf);
                u32 q3 = cvtpk(fmaxf(a[6], 0.f) * mf, fmaxf(a[7], 0.f) * mf);
                *(uint4*)(hb + j * 16) = make_uint4(q0, q1, q2, q3);
                #pragma unroll
                for (int r = 0; r < 3; ++r) { c0[r] = c1[r]; c1[r] = c2[r]; }
            }
        }
    }
    __syncthreads();

    // conv2 weights/bias into regs
    bf16x8 wf[9][4];
    #pragma unroll
    for (int tap = 0; tap < 9; ++tap)
        #pragma unroll
        for (int nt = 0; nt < 4; ++nt)
            wf[tap][nt] = *(const bf16x8*)(w2b + tap * 2048 + (nt * 16 + lr) * 32 + lg * 8);
    float bias2[4];
    #pragma unroll
    for (int nt = 0; nt < 4; ++nt) bias2[nt] = b2[nt * 16 + lr];

    const int cb = wv & 1;
    const int r0 = wv >> 1;
    const char* gb = (const char*)h1 + lg * 14464 + (cb * 16 + lr) * 16;
    const bool store_ok = !(cb == 1 && lg == 3);
    const int pc0 = cb * 8 + lg * 2;
    u16* poolb = pooled + (size_t)b * 12544;

    #pragma unroll 1
    for (int i = 0; i < 7; ++i) {
        const int r = r0 + 2 * i;
        const char* ab = gb + 960 * r;
        bf16x8 a0[3], a1[3], a2[3], a3[3];
        #pragma unroll
        for (int kw = 0; kw < 3; ++kw) {
            a0[kw] = *(const bf16x8*)(ab + kw * 16);
            a1[kw] = *(const bf16x8*)(ab + 480 + kw * 16);
            a2[kw] = *(const bf16x8*)(ab + 960 + kw * 16);
        }
        f32x4 acc0[4], acc1[4];
        #pragma unroll
        for (int nt = 0; nt < 4; ++nt) {
            acc0[nt] = (f32x4){bias2[nt], bias2[nt], bias2[nt], bias2[nt]};
            acc1[nt] = acc0[nt];
        }
        #pragma unroll
        for (int nt = 0; nt < 4; ++nt)
            #pragma unroll
            for (int kw = 0; kw < 3; ++kw) {
                acc0[nt] = __builtin_amdgcn_mfma_f32_16x16x32_bf16(a0[kw], wf[kw][nt], acc0[nt], 0, 0, 0);
                acc0[nt] = __builtin_amdgcn_mfma_f32_16x16x32_bf16(a1[kw], wf[3 + kw][nt], acc0[nt], 0, 0, 0);
                acc0[nt] = __builtin_amdgcn_mfma_f32_16x16x32_bf16(a2[kw], wf[6 + kw][nt], acc0[nt], 0, 0, 0);
            }
        #pragma unroll
        for (int kw = 0; kw < 3; ++kw)
            a3[kw] = *(const bf16x8*)(ab + 1440 + kw * 16);
        #pragma unroll
        for (int nt = 0; nt < 4; ++nt)
            #pragma unroll
            for (int kw = 0; kw < 3; ++kw) {
                acc1[nt] = __builtin_amdgcn_mfma_f32_16x16x32_bf16(a1[kw], wf[kw][nt], acc1[nt], 0, 0, 0);
                acc1[nt] = __builtin_amdgcn_mfma_f32_16x16x32_bf16(a2[kw], wf[3 + kw][nt], acc1[nt], 0, 0, 0);
                acc1[nt] = __builtin_amdgcn_mfma_f32_16x16x32_bf16(a3[kw], wf[6 + kw][nt], acc1[nt], 0, 0, 0);
            }

        if (store_ok) {
            u32 pmw = *(const u16*)&pm[r * 14 + pc0];
            float m00 = (pmw & 1u)    ? 1.f : 0.f, m01 = (pmw & 2u)    ? 1.f : 0.f;
            float m10 = (pmw & 4u)    ? 1.f : 0.f, m11 = (pmw & 8u)    ? 1.f : 0.f;
            float n00 = (pmw & 256u)  ? 1.f : 0.f, n01 = (pmw & 512u)  ? 1.f : 0.f;
            float n10 = (pmw & 1024u) ? 1.f : 0.f, n11 = (pmw & 2048u) ? 1.f : 0.f;
            #pragma unroll
            for (int nt = 0; nt < 4; ++nt) {
                float p0 = fmaxf(fmaxf(fmaxf(acc0[nt][0], 0.f) * m00, fmaxf(acc0[nt][1], 0.f) * m01),
                                 fmaxf(fmaxf(acc1[nt][0], 0.f) * m10, fmaxf(acc1[nt][1], 0.f) * m11));
                float p1 = fmaxf(fmaxf(fmaxf(acc0[nt][2], 0.f) * n00, fmaxf(acc0[nt][3], 0.f) * n01),
                                 fmaxf(fmaxf(acc1[nt][2], 0.f) * n10, fmaxf(acc1[nt][3], 0.f) * n11));
                *(u32*)&poolb[(nt * 16 + lr) * 196 + r * 14 + pc0] = cvtpk(p0, p1);
            }
        }
    }
}

// ---------------- Kernel 4: FC1 MFMA GEMM (BM=64,BN=128,BK=64,splitK=7, slab outputs)
__global__ __launch_bounds__(256, 4) void k_fc1(const u16* __restrict__ pooled,
    const u16* __restrict__ fcw1b, float* __restrict__ fc1p, int M)
{
    __shared__ u16 Asm[8 * 64 * 8];
    __shared__ u16 Bsm[8 * 128 * 8];
    const int t = threadIdx.x;
    const int m0 = blockIdx.x * 64;
    const int kbase = blockIdx.y * 1792;
    const int lane = t & 63;
    const int wv = t >> 6;
    const int lg = lane >> 4, lr = lane & 15;
    const int wm = wv & 1, wn = wv >> 1;

    const int ia0 = t, ia1 = t + 256;
    const u16* as0 = pooled + (size_t)(m0 + (ia0 & 63)) * 12544 + (ia0 >> 6) * 8 + kbase;
    const u16* as1 = pooled + (size_t)(m0 + (ia1 & 63)) * 12544 + (ia1 >> 6) * 8 + kbase;
    const u16* bs0 = fcw1b + (size_t)(t & 127) * 12544 + ((t >> 7) + 0) * 8 + kbase;
    const u16* bs1 = fcw1b + (size_t)(t & 127) * 12544 + ((t >> 7) + 2) * 8 + kbase;
    const u16* bs2 = fcw1b + (size_t)(t & 127) * 12544 + ((t >> 7) + 4) * 8 + kbase;
    const u16* bs3 = fcw1b + (size_t)(t & 127) * 12544 + ((t >> 7) + 6) * 8 + kbase;
    u16* ad0 = &Asm[(size_t)ia0 * 8];
    u16* ad1 = &Asm[(size_t)ia1 * 8];
    u16* bd0 = &Bsm[(size_t)(t + 0) * 8];
    u16* bd1 = &Bsm[(size_t)(t + 256) * 8];
    u16* bd2 = &Bsm[(size_t)(t + 512) * 8];
    u16* bd3 = &Bsm[(size_t)(t + 768) * 8];

    f32x4 acc[2][4];
    #pragma unroll
    for (int mi = 0; mi < 2; ++mi)
        #pragma unroll
        for (int ni = 0; ni < 4; ++ni) acc[mi][ni] = (f32x4){0.f, 0.f, 0.f, 0.f};

    for (int s = 0; s < 28; ++s) {
        const int kk = s * 64;
        __syncthreads();
        gload16(as0 + kk, ad0);
        gload16(as1 + kk, ad1);
        gload16(bs0 + kk, bd0);
        gload16(bs1 + kk, bd1);
        gload16(bs2 + kk, bd2);
        gload16(bs3 + kk, bd3);
        asm volatile("s_waitcnt vmcnt(0)" ::: "memory");
        __syncthreads();
        #pragma unroll
        for (int ks = 0; ks < 2; ++ks) {
            bf16x8 a[2], bfr[4];
            #pragma unroll
            for (int mi = 0; mi < 2; ++mi)
                a[mi] = *(const bf16x8*)&Asm[(((ks * 4 + lg) * 64) + wm * 32 + mi * 16 + lr) * 8];
            #pragma unroll
            for (int ni = 0; ni < 4; ++ni)
                bfr[ni] = *(const bf16x8*)&Bsm[(((ks * 4 + lg) * 128) + wn * 64 + ni * 16 + lr) * 8];
            #pragma unroll
            for (int mi = 0; mi < 2; ++mi)
                #pragma unroll
                for (int ni = 0; ni < 4; ++ni)
                    acc[mi][ni] = __builtin_amdgcn_mfma_f32_16x16x32_bf16(a[mi], bfr[ni], acc[mi][ni], 0, 0, 0);
        }
    }

    float* outp = fc1p + (size_t)blockIdx.y * M * 128;
    #pragma unroll
    for (int mi = 0; mi < 2; ++mi)
        #pragma unroll
        for (int ni = 0; ni < 4; ++ni)
            #pragma unroll
            for (int q = 0; q < 4; ++q) {
                int m = m0 + wm * 32 + mi * 16 + lg * 4 + q;
                int n = wn * 64 + ni * 16 + lr;
                outp[(size_t)m * 128 + n] = acc[mi][ni][q];
            }
}

// ---------------- Kernel 5: slab-sum + bias+ReLU + FC2 + log_softmax
__global__ __launch_bounds__(256) void k_fc2(const float* __restrict__ fc1p,
    const float* __restrict__ fcb1, const float* __restrict__ fcw2,
    const float* __restrict__ fcb2, float* __restrict__ out, int M)
{
    __shared__ float red[8][32][10];
    const int t = threadIdx.x;
    const int ml = t & 31, kq = t >> 5;
    const int m = blockIdx.x * 32 + ml;
    const size_t slab = (size_t)M * 128;
    float acc[10];
    #pragma unroll
    for (int c = 0; c < 10; ++c) acc[c] = 0.f;
    const float* fp = fc1p + (size_t)m * 128 + kq * 16;
    #pragma unroll
    for (int j = 0; j < 16; j += 4) {
        float4 v4 = *(const float4*)(fp + j);
        #pragma unroll
        for (int s = 1; s < 7; ++s) {
            float4 u4 = *(const float4*)(fp + s * slab + j);
            v4.x += u4.x; v4.y += u4.y; v4.z += u4.z; v4.w += u4.w;
        }
        float vv[4] = {v4.x, v4.y, v4.z, v4.w};
        #pragma unroll
        for (int u = 0; u < 4; ++u) {
            int k = kq * 16 + j + u;
            float v = fmaxf(vv[u] + fcb1[k], 0.f);
            #pragma unroll
            for (int c = 0; c < 10; ++c) acc[c] = fmaf(v, fcw2[c * 128 + k], acc[c]);
        }
    }
    #pragma unroll
    for (int c = 0; c < 10; ++c) red[kq][ml][c] = acc[c];
    __syncthreads();
    if (kq == 0) {
        float lgt[10];
        #pragma unroll
        for (int c = 0; c < 10; ++c) {
            float sv = 0.f;
            #pragma unroll
            for (int s = 0; s < 8; ++s) sv += red[s][ml][c];
            lgt[c] = sv + fcb2[c];
        }
        float mx = lgt[0];
        #pragma unroll
        for (int c = 1; c < 10; ++c) mx = fmaxf(mx, lgt[c]);
        float se = 0.f;
        #pragma unroll
        for (int c = 0; c < 10; ++c) se += expf(lgt[c] - mx);
        float lse = mx + logf(se);
        #pragma unroll
        for (int c = 0; c < 10; ++c) out[(size_t)m * 10 + c] = lgt[c] - lse;
    }
}

extern "C" void kernel_launch(void* const* d_in, const int* in_sizes, int n_in,
                              void* d_out, int out_size, void* d_ws, size_t ws_size,
                              hipStream_t stream) {
    const float* x     = (const float*)d_in[0];
    const float* gamma = (const float*)d_in[1];
    const float* beta  = (const float*)d_in[2];
    const float* w1    = (const float*)d_in[3];
    const float* b1    = (const float*)d_in[4];
    const float* w2    = (const float*)d_in[5];
    const float* b2    = (const float*)d_in[6];
    const float* fcw1  = (const float*)d_in[7];
    const float* fcb1  = (const float*)d_in[8];
    const float* fcw2  = (const float*)d_in[9];
    const float* fcb2  = (const float*)d_in[10];
    float* out = (float*)d_out;

    const int B = in_sizes[0] / 784;  // 4096
    char* base = (char*)d_ws;

    // ws: stats(256) | w2b(36864) | fc1p[7][B][128] f32 (14.68MB) | pooled (102.8MB)
    //     | fcw1b (3.2MB)  -> total ~120.7MB  (ws_size >= 136MB proven in R8)
    float* stats  = (float*)base;
    u16*   w2b    = (u16*)(base + 256);
    float* fc1p   = (float*)(base + 37376);
    u16*   pooled = (u16*)(base + 37376 + (size_t)7 * B * 128 * 4);
    u16*   fcw1b  = (u16*)(base + 37376 + (size_t)7 * B * 128 * 4 + (size_t)B * 12544 * 2);

    hipMemsetAsync(stats, 0, 32, stream);
    k_stats<<<1024, 256, 0, stream>>>(x, B * 784, stats);
    k_finalize<<<1, 1, 0, stream>>>(gamma, beta, stats);
    k_prepall<<<1568, 256, 0, stream>>>(w2, fcw1, w2b, fcw1b, 128 * 12544 / 4);
    k_conv<<<B, 256, 0, stream>>>(x, w1, b1, w2b, b2, stats, pooled);
    k_fc1<<<dim3(B / 64, 7), 256, 0, stream>>>(pooled, fcw1b, fc1p, B);
    k_fc2<<<B / 32, 256, 0, stream>>>(fc1p, fcb1, fcw2, fcb2, out, B);
}